// Round 2
// baseline (356.981 us; speedup 1.0000x reference)
//
#include <hip/hip_runtime.h>

// TopK_36653250904599: x [16,256,128,128] f32 -> l2-normalize over HW=16384,
// top-16 values [B,C,16] + (h,w) coords [B,C,16,2] (coords stored as floats).
//
// R8: single launch (R7 structure), streaming phase rebuilt.
// Post-mortem R7: fills are per-ITERATION harness poison (fusing launches
// saved only 12 us); k_fused is <159 us (absent from top-5) and estimated
// ~80-100 us vs a 42-us HBM floor for the 268-MB read. Two streaming fixes:
//   (1) issue all 16 dwordx4 loads per thread up front (256 B/thread in
//       flight) instead of 4-load bursts punctuated by dependent mask/atomic
//       work -- the load pipe no longer drains between quarters. VGPR ~100
//       -> 4 blocks/CU (16 waves), still >> latency-hiding requirement.
//   (2) plain cached loads instead of __builtin_nontemporal_load -- nt
//       bypasses L2/L3 and forfeits any residency the harness restore left.
// Numerics bitwise-identical to R6/R7: per-quarter fma chain order, 64-lane
// shfl tree, wave-then-quarter add order, packing, idx tiebreak, fallback.
// Candidate list ORDER is irrelevant (rank compares packed values, unique).

#define KSEL 16
#define HW   16384
#define WDIM 128
#define CAP  1024
#define T0   2.5f
#define NROWS 4096
#define VALS_TOTAL (NROWS * KSEL)   // 65536 value floats, then coords

typedef float floatx4 __attribute__((ext_vector_type(4)));

__global__ __launch_bounds__(256) void k_fused(const float* __restrict__ x,
                                               float* __restrict__ out) {
    const int row  = blockIdx.x;
    const int t    = threadIdx.x;
    const int lane = t & 63;
    const int wv   = t >> 6;

    __shared__ unsigned long long s_cand[CAP];
    __shared__ float s_part[4][4];      // [quarter][wave]
    __shared__ unsigned s_cnt;

    if (t == 0) s_cnt = 0;
    __syncthreads();

    const floatx4* p = (const floatx4*)(x + (size_t)row * HW);

    // ---- streaming phase: all 16 loads issued before any dependent use ----
    floatx4 buf[16];
    #pragma unroll
    for (int kk = 0; kk < 16; ++kk)
        buf[kk] = p[kk * 256 + t];      // plain cached loads (no nt)

    // per-quarter sq-sums, exact fma order of R6/R7
    float sqsum[4];
    #pragma unroll
    for (int c = 0; c < 4; ++c) {
        float s = 0.0f;
        #pragma unroll
        for (int k = 0; k < 4; ++k) {
            const floatx4 b = buf[c * 4 + k];
            s = fmaf(b.x, b.x, s);
            s = fmaf(b.y, b.y, s);
            s = fmaf(b.z, b.z, s);
            s = fmaf(b.w, b.w, s);
        }
        sqsum[c] = s;
    }

    // per-quarter candidate mask + one reservation atomic + predicated pushes
    #pragma unroll
    for (int c = 0; c < 4; ++c) {
        unsigned msk = 0;
        #pragma unroll
        for (int k = 0; k < 4; ++k) {
            const floatx4 b = buf[c * 4 + k];
            msk |= (b.x > T0) ? (1u << (4 * k + 0)) : 0u;
            msk |= (b.y > T0) ? (1u << (4 * k + 1)) : 0u;
            msk |= (b.z > T0) ? (1u << (4 * k + 2)) : 0u;
            msk |= (b.w > T0) ? (1u << (4 * k + 3)) : 0u;
        }
        if (msk) {
            unsigned base = atomicAdd(&s_cnt, (unsigned)__popc(msk));
            #pragma unroll
            for (int k = 0; k < 4; ++k) {
                #pragma unroll
                for (int cc = 0; cc < 4; ++cc) {
                    const floatx4 b = buf[c * 4 + k];
                    float v = (cc == 0) ? b.x : (cc == 1) ? b.y
                            : (cc == 2) ? b.z : b.w;
                    if (v > T0) {
                        if (base < CAP) {
                            unsigned u  = __float_as_uint(v);
                            unsigned mm = u ^ (((unsigned)((int)u >> 31)) | 0x80000000u);
                            int idx = c * 4096 + (k * 256 + t) * 4 + cc; // in-row idx
                            s_cand[base] = ((unsigned long long)mm << 32) |
                                           (unsigned)(16383 - idx);
                        }
                        base++;
                    }
                }
            }
        }
    }

    // ---- per-quarter wave-tree reduction (same order as R6/R7) ----
    #pragma unroll
    for (int c = 0; c < 4; ++c) {
        float s = sqsum[c];
        #pragma unroll
        for (int off = 32; off > 0; off >>= 1)
            s += __shfl_down(s, off, 64);
        if (lane == 0) s_part[c][wv] = s;
    }
    __syncthreads();    // s_part + all candidate pushes visible

    // same add order: qsum[c] = ((w0+w1)+w2)+w3; total = ((q0+q1)+q2)+q3
    const float q0 = s_part[0][0] + s_part[0][1] + s_part[0][2] + s_part[0][3];
    const float q1 = s_part[1][0] + s_part[1][1] + s_part[1][2] + s_part[1][3];
    const float q2 = s_part[2][0] + s_part[2][1] + s_part[2][2] + s_part[2][3];
    const float q3 = s_part[3][0] + s_part[3][1] + s_part[3][2] + s_part[3][3];
    const float scale = 1.0f / sqrtf(fmaxf(q0 + q1 + q2 + q3, 1e-12f));

    unsigned cnt = s_cnt;   // uniform: read after barrier, no writes since

    if (cnt < KSEL || cnt > CAP) {
        // slow path (never for N(0,1)): bisect raw threshold, re-reading row
        const float* xr = x + (size_t)row * HW;
        float T = T0, lo = -3.0e38f, hi = 3.0e38f;
        for (int it = 0; it < 32; ++it) {
            __syncthreads();
            if (t == 0) s_cnt = 0;
            __syncthreads();
            for (int i = t; i < HW; i += 256) {
                float v = xr[i];
                if (v > T) {
                    unsigned slot = atomicAdd(&s_cnt, 1u);
                    if (slot < CAP) {
                        unsigned u  = __float_as_uint(v);
                        unsigned mm = u ^ (((unsigned)((int)u >> 31)) | 0x80000000u);
                        s_cand[slot] = ((unsigned long long)mm << 32) |
                                       (unsigned)(16383 - i);
                    }
                }
            }
            __syncthreads();
            cnt = s_cnt;
            if (cnt >= KSEL && cnt <= CAP) break;
            if (cnt < KSEL) { hi = T; T = (lo < -1.0e38f) ? T - 1.0f : 0.5f * (lo + T); }
            else            { lo = T; T = (hi >  1.0e38f) ? T + 1.0f : 0.5f * (T + hi); }
        }
        if (cnt > CAP) cnt = CAP;
    }

    // repack with normalized fp32-rounded value (rounding ties -> idx-asc
    // tiebreak in low bits matches jax.lax.top_k)
    for (unsigned i = t; i < cnt; i += 256) {
        unsigned long long pk = s_cand[i];
        unsigned m = (unsigned)(pk >> 32);
        unsigned u = (m & 0x80000000u) ? (m ^ 0x80000000u) : ~m;
        float vn = __uint_as_float(u) * scale;
        unsigned u2 = __float_as_uint(vn);
        unsigned m2 = u2 ^ (((unsigned)((int)u2 >> 31)) | 0x80000000u);
        s_cand[i] = ((unsigned long long)m2 << 32) | (pk & 0xFFFFFFFFull);
    }
    __syncthreads();

    // all-pairs rank (ranks unique via idx tiebreak) + write
    for (unsigned i = t; i < cnt; i += 256) {
        unsigned long long pk = s_cand[i];
        int rank = 0;
        for (unsigned j = 0; j < cnt; ++j) rank += (s_cand[j] > pk) ? 1 : 0;
        if (rank < KSEL) {
            unsigned m = (unsigned)(pk >> 32);
            unsigned u = (m & 0x80000000u) ? (m ^ 0x80000000u) : ~m;
            float vn = __uint_as_float(u);
            int idx = 16383 - (int)(unsigned)(pk & 0xFFFFFFFFull);
            out[row * KSEL + rank] = vn;
            float* coor = out + VALS_TOTAL + ((size_t)row * KSEL + rank) * 2;
            coor[0] = (float)(idx >> 7);          // h
            coor[1] = (float)(idx & (WDIM - 1));  // w
        }
    }
}

extern "C" void kernel_launch(void* const* d_in, const int* in_sizes, int n_in,
                              void* d_out, int out_size, void* d_ws, size_t ws_size,
                              hipStream_t stream) {
    const float* x = (const float*)d_in[0];
    float* out = (float*)d_out;
    (void)d_ws; (void)ws_size;  // workspace unused: single self-contained launch
    k_fused<<<NROWS, 256, 0, stream>>>(x, out);
}

// Round 3
// 331.321 us; speedup vs baseline: 1.0774x; 1.0774x over previous
//
#include <hip/hip_runtime.h>

// TopK_36653250904599: x [16,256,128,128] f32 -> l2-normalize over HW=16384,
// top-16 values [B,C,16] + (h,w) coords [B,C,16,2] (coords stored as floats).
//
// R9: R7 body (best-known, 331 us) + ONE change: 2-deep register pipeline on
// the streaming quarters. R8 post-mortem: hoisting all 16 loads (64 VGPR
// live) cut occupancy 8->4 blocks/CU and dropping nontemporal loads thrashed
// L2 -- both reverted. Here quarter c+1's 4 nt-loads are issued BEFORE the
// dependent work (fma chain + divergent mask/atomic/push) of quarter c, so
// the load pipe never drains; cost is +16 VGPR (double buffer), keeping
// ~7-8 blocks/CU. One 1-GiB harness poison fill (~161 us) is in the timed
// path and untouchable; kernel share is ~60-130 us vs a 42-us read floor.
// Numerics bitwise-identical to R6/R7: per-quarter fma chain order, 64-lane
// shfl tree, wave-then-quarter add order, packing, idx tiebreak, fallback.
// Candidate list ORDER is irrelevant (rank compares packed values, unique).

#define KSEL 16
#define HW   16384
#define WDIM 128
#define CAP  1024
#define T0   2.5f
#define NROWS 4096
#define VALS_TOTAL (NROWS * KSEL)   // 65536 value floats, then coords

typedef float floatx4 __attribute__((ext_vector_type(4)));

__global__ __launch_bounds__(256) void k_fused(const float* __restrict__ x,
                                               float* __restrict__ out) {
    const int row  = blockIdx.x;
    const int t    = threadIdx.x;
    const int lane = t & 63;
    const int wv   = t >> 6;

    __shared__ unsigned long long s_cand[CAP];
    __shared__ float s_part[4][4];      // [quarter][wave]
    __shared__ unsigned s_cnt;

    if (t == 0) s_cnt = 0;
    __syncthreads();

    const floatx4* p = (const floatx4*)(x + (size_t)row * HW);

    float sqsum[4];

    // process quarter c from a 4-float4 register buffer; exact R7 order
    auto process = [&](const floatx4* buf, int c) {
        float s = 0.0f;
        #pragma unroll
        for (int k = 0; k < 4; ++k) {
            s = fmaf(buf[k].x, buf[k].x, s);
            s = fmaf(buf[k].y, buf[k].y, s);
            s = fmaf(buf[k].z, buf[k].z, s);
            s = fmaf(buf[k].w, buf[k].w, s);
        }
        sqsum[c] = s;

        unsigned msk = 0;
        #pragma unroll
        for (int k = 0; k < 4; ++k) {
            msk |= (buf[k].x > T0) ? (1u << (4 * k + 0)) : 0u;
            msk |= (buf[k].y > T0) ? (1u << (4 * k + 1)) : 0u;
            msk |= (buf[k].z > T0) ? (1u << (4 * k + 2)) : 0u;
            msk |= (buf[k].w > T0) ? (1u << (4 * k + 3)) : 0u;
        }
        if (msk) {
            unsigned base = atomicAdd(&s_cnt, (unsigned)__popc(msk));
            #pragma unroll
            for (int k = 0; k < 4; ++k) {
                #pragma unroll
                for (int cc = 0; cc < 4; ++cc) {
                    float v = (cc == 0) ? buf[k].x : (cc == 1) ? buf[k].y
                            : (cc == 2) ? buf[k].z : buf[k].w;
                    if (v > T0) {
                        if (base < CAP) {
                            unsigned u  = __float_as_uint(v);
                            unsigned mm = u ^ (((unsigned)((int)u >> 31)) | 0x80000000u);
                            int idx = c * 4096 + (k * 256 + t) * 4 + cc; // in-row idx
                            s_cand[base] = ((unsigned long long)mm << 32) |
                                           (unsigned)(16383 - idx);
                        }
                        base++;
                    }
                }
            }
        }
    };

    // ---- streaming: 2-deep pipeline, next quarter's loads issued before
    //      current quarter's dependent work ----
    floatx4 bufA[4], bufB[4];
    #pragma unroll
    for (int k = 0; k < 4; ++k)
        bufA[k] = __builtin_nontemporal_load(&p[0 * 1024 + k * 256 + t]);
    #pragma unroll
    for (int k = 0; k < 4; ++k)
        bufB[k] = __builtin_nontemporal_load(&p[1 * 1024 + k * 256 + t]);
    process(bufA, 0);
    #pragma unroll
    for (int k = 0; k < 4; ++k)
        bufA[k] = __builtin_nontemporal_load(&p[2 * 1024 + k * 256 + t]);
    process(bufB, 1);
    #pragma unroll
    for (int k = 0; k < 4; ++k)
        bufB[k] = __builtin_nontemporal_load(&p[3 * 1024 + k * 256 + t]);
    process(bufA, 2);
    process(bufB, 3);

    // ---- per-quarter wave-tree reduction (same order as R6/R7) ----
    #pragma unroll
    for (int c = 0; c < 4; ++c) {
        float s = sqsum[c];
        #pragma unroll
        for (int off = 32; off > 0; off >>= 1)
            s += __shfl_down(s, off, 64);
        if (lane == 0) s_part[c][wv] = s;
    }
    __syncthreads();    // s_part + all candidate pushes visible

    // same add order: qsum[c] = ((w0+w1)+w2)+w3; total = ((q0+q1)+q2)+q3
    const float q0 = s_part[0][0] + s_part[0][1] + s_part[0][2] + s_part[0][3];
    const float q1 = s_part[1][0] + s_part[1][1] + s_part[1][2] + s_part[1][3];
    const float q2 = s_part[2][0] + s_part[2][1] + s_part[2][2] + s_part[2][3];
    const float q3 = s_part[3][0] + s_part[3][1] + s_part[3][2] + s_part[3][3];
    const float scale = 1.0f / sqrtf(fmaxf(q0 + q1 + q2 + q3, 1e-12f));

    unsigned cnt = s_cnt;   // uniform: read after barrier, no writes since

    if (cnt < KSEL || cnt > CAP) {
        // slow path (never for N(0,1)): bisect raw threshold, re-reading row
        const float* xr = x + (size_t)row * HW;
        float T = T0, lo = -3.0e38f, hi = 3.0e38f;
        for (int it = 0; it < 32; ++it) {
            __syncthreads();
            if (t == 0) s_cnt = 0;
            __syncthreads();
            for (int i = t; i < HW; i += 256) {
                float v = xr[i];
                if (v > T) {
                    unsigned slot = atomicAdd(&s_cnt, 1u);
                    if (slot < CAP) {
                        unsigned u  = __float_as_uint(v);
                        unsigned mm = u ^ (((unsigned)((int)u >> 31)) | 0x80000000u);
                        s_cand[slot] = ((unsigned long long)mm << 32) |
                                       (unsigned)(16383 - i);
                    }
                }
            }
            __syncthreads();
            cnt = s_cnt;
            if (cnt >= KSEL && cnt <= CAP) break;
            if (cnt < KSEL) { hi = T; T = (lo < -1.0e38f) ? T - 1.0f : 0.5f * (lo + T); }
            else            { lo = T; T = (hi >  1.0e38f) ? T + 1.0f : 0.5f * (T + hi); }
        }
        if (cnt > CAP) cnt = CAP;
    }

    // repack with normalized fp32-rounded value (rounding ties -> idx-asc
    // tiebreak in low bits matches jax.lax.top_k)
    for (unsigned i = t; i < cnt; i += 256) {
        unsigned long long pk = s_cand[i];
        unsigned m = (unsigned)(pk >> 32);
        unsigned u = (m & 0x80000000u) ? (m ^ 0x80000000u) : ~m;
        float vn = __uint_as_float(u) * scale;
        unsigned u2 = __float_as_uint(vn);
        unsigned m2 = u2 ^ (((unsigned)((int)u2 >> 31)) | 0x80000000u);
        s_cand[i] = ((unsigned long long)m2 << 32) | (pk & 0xFFFFFFFFull);
    }
    __syncthreads();

    // all-pairs rank (ranks unique via idx tiebreak) + write
    for (unsigned i = t; i < cnt; i += 256) {
        unsigned long long pk = s_cand[i];
        int rank = 0;
        for (unsigned j = 0; j < cnt; ++j) rank += (s_cand[j] > pk) ? 1 : 0;
        if (rank < KSEL) {
            unsigned m = (unsigned)(pk >> 32);
            unsigned u = (m & 0x80000000u) ? (m ^ 0x80000000u) : ~m;
            float vn = __uint_as_float(u);
            int idx = 16383 - (int)(unsigned)(pk & 0xFFFFFFFFull);
            out[row * KSEL + rank] = vn;
            float* coor = out + VALS_TOTAL + ((size_t)row * KSEL + rank) * 2;
            coor[0] = (float)(idx >> 7);          // h
            coor[1] = (float)(idx & (WDIM - 1));  // w
        }
    }
}

extern "C" void kernel_launch(void* const* d_in, const int* in_sizes, int n_in,
                              void* d_out, int out_size, void* d_ws, size_t ws_size,
                              hipStream_t stream) {
    const float* x = (const float*)d_in[0];
    float* out = (float*)d_out;
    (void)d_ws; (void)ws_size;  // workspace unused: single self-contained launch
    k_fused<<<NROWS, 256, 0, stream>>>(x, out);
}